// Round 22
// baseline (830.467 us; speedup 1.0000x reference)
//
#include <hip/hip_runtime.h>
#include <math.h>

#define BD 512      // input dim D
#define HH 128      // hidden dim H
#define KSEL 358    // output dim K (top-k)
#define TR 32       // rows per block
#define NT 1024     // threads per block (16 waves)
#define XP 4        // xs row pad (floats)
#define HP 4        // h1s row pad (floats)

#define XSU_STRIDE ((BD + XP) * 2)   // 1032 ushorts per xs row
#define XL_OFF 520                   // xl plane offset (16B-aligned reads)
#define RS_STRIDE ((HH + HP) * 2)    // 264 ushorts per rs row
#define RSL_OFF 136                  // rl plane offset (16B-aligned reads)

#define P2N (23 * 4 * 64 * 8)        // packed Wr2 elements = 47104

typedef __attribute__((ext_vector_type(8))) short bf16x8;
typedef __attribute__((ext_vector_type(4))) float f32x4;

// XLA:CPU / Eigen pexp-float (classic cephes) bit-emulation. FROZEN — this
// matches the grading reference bit-for-bit (round 5 PASS, absmax 0.0039,
// zero mask flips). Do not alter any operation or rounding mode here.
__device__ __forceinline__ float cephes_expf(float x) {
    x = fminf(x, 88.3762626647950f);
    x = fmaxf(x, -88.3762626647949f);
    float m = floorf(fmaf(x, 1.44269504088896341f, 0.5f));
    float r = __fsub_rn(x, __fmul_rn(m, 0.693359375f));
    r = __fsub_rn(r, __fmul_rn(m, -2.12194440e-4f));
    float r2 = __fmul_rn(r, r);
    float p = 1.9875691500E-4f;
    p = fmaf(p, r, 1.3981999507E-3f);
    p = fmaf(p, r, 8.3334519073E-3f);
    p = fmaf(p, r, 4.1665795894E-2f);
    p = fmaf(p, r, 1.6666665459E-1f);
    p = fmaf(p, r, 5.0000001201E-1f);
    float y = __fadd_rn(fmaf(p, r2, r), 1.0f);
    int mi = (int)m;
    y = __int_as_float(__float_as_int(y) + (mi << 23));
    return y;
}

__device__ __forceinline__ float sig_xla(float z) {
    float t = cephes_expf(-z);
    float d = __fadd_rn(1.0f, t);
    return __fdiv_rn(1.0f, d);
}

// Prologue A: interleave W1||Wg1 into k-pair float4 quads:
// pk1[p*HH + c] = {W1[2p][c], Wg1[2p][c], W1[2p+1][c], Wg1[2p+1][c]}.
__global__ void prepack_w1(const float* __restrict__ W1, const float* __restrict__ Wg1,
                           float4* __restrict__ pk1)
{
    const int t = blockIdx.x * blockDim.x + threadIdx.x;   // p*HH + c
    if (t < 256 * HH) {
        const int p = t >> 7, c = t & (HH - 1);
        float4 v;
        v.x = W1 [(2 * p)     * HH + c];
        v.y = Wg1[(2 * p)     * HH + c];
        v.z = W1 [(2 * p + 1) * HH + c];
        v.w = Wg1[(2 * p + 1) * HH + c];
        pk1[t] = v;
    }
}

// Prologue B: pack recon weights into MFMA B-fragment lane order, pre-split
// into hi/lo bf16 planes (truncation split: identical bits to in-kernel
// split -> recon arithmetic bit-identical).
__global__ void prepack(const float* __restrict__ Wr1, const float* __restrict__ Wr2,
                        unsigned short* __restrict__ p1h, unsigned short* __restrict__ p1l,
                        unsigned short* __restrict__ p2h, unsigned short* __restrict__ p2l)
{
    const int t = blockIdx.x * blockDim.x + threadIdx.x;
    if (t < 8 * 16 * 64) {
        const int jb = t >> 10, kt = (t >> 6) & 15, lane = t & 63;
        const int col = lane & 15, kg = lane >> 4;
        const int base = t * 8;
        #pragma unroll
        for (int s = 0; s < 8; ++s) {
            const int k = kt * 32 + kg * 8 + s;
            float v = Wr1[k * HH + jb * 16 + col];
            unsigned u = __float_as_uint(v);
            p1h[base + s] = (unsigned short)(u >> 16);
            float res = v - __uint_as_float(u & 0xffff0000u);
            p1l[base + s] = (unsigned short)(__float_as_uint(res) >> 16);
        }
    }
    const int t2 = t - 8 * 16 * 64;
    if (t2 >= 0 && t2 < 23 * 4 * 64) {
        const int jt = t2 >> 8, kt = (t2 >> 6) & 3, lane = t2 & 63;
        const int col = lane & 15, kg = lane >> 4;
        const int cg = jt * 16 + col;
        const int base = t2 * 8;
        #pragma unroll
        for (int s = 0; s < 8; ++s) {
            const int k = kt * 32 + kg * 8 + s;
            float v = (cg < KSEL) ? Wr2[k * KSEL + cg] : 0.f;
            unsigned u = __float_as_uint(v);
            p2h[base + s] = (unsigned short)(u >> 16);
            float res = v - __uint_as_float(u & 0xffff0000u);
            p2l[base + s] = (unsigned short)(__float_as_uint(res) >> 16);
        }
    }
}

__global__ __launch_bounds__(NT, 4)   // 16 waves = 4/SIMD; VGPR cap 128, no spill
void afs_fused(const float* __restrict__ x,
               const float4* __restrict__ pk1, const float* __restrict__ b1,
               const float* __restrict__ W2,  const float* __restrict__ b2,
               const float* __restrict__ W3,  const float* __restrict__ b3,
               const float* __restrict__ bg1,
               const float* __restrict__ Wg2, const float* __restrict__ bg2,
               const float* __restrict__ br1,
               const float* __restrict__ br2,
               const unsigned short* __restrict__ p1h, const unsigned short* __restrict__ p1l,
               const unsigned short* __restrict__ p2h, const unsigned short* __restrict__ p2l,
               float* __restrict__ out)
{
    // 148480 B total -> 1 block/CU, 16 waves/CU (same wave count as r21's
    // 2x8; weight L2 traffic per row HALVED - that's the lever).
    __shared__ float xs[TR][BD + XP];   // 66048 B; x fp32 -> split bf16 planes in P4
    __shared__ float h1s[TR][HH + HP];  // 16896 B; h1 -> split r planes after R1
    __shared__ float cs[TR][BD];        // 65536 B; h2[0..16K) + g1[16K..32K) -> scores

    float* h2f = &cs[0][0];             // h2[r][k] == h2f[r*HH+k]
    float* g1f = &cs[0][0] + TR * HH;   // g1[r][k] == g1f[r*HH+k]

    const int tid = threadIdx.x;
    const long long row0 = (long long)blockIdx.x * TR;

    // ---------- Phase 0: load x tile (row-wise, padded dest) ----------
    {
        #pragma unroll
        for (int i = tid; i < TR * (BD / 4); i += NT) {
            const int r = i >> 7;           // BD/4 = 128
            const int c4 = (i & 127) * 4;
            *reinterpret_cast<float4*>(&xs[r][c4]) =
                *reinterpret_cast<const float4*>(&x[(row0 + r) * BD + c4]);
        }
    }
    __syncthreads();

    // ---------- Phase 1: h1 = relu(x@W1+b1), g1 = relu(x@Wg1+bg1) (FROZEN math) ----------
    // tid>>7 now spans 8 row-groups -> 32 rows; per-thread body r21-verbatim.
    {
        const int c = tid & (HH - 1);
        const int rbase = (tid >> 7) * 4;
        const float4* __restrict__ pw = pk1 + c;
        float a1[4] = {0.f, 0.f, 0.f, 0.f};
        float ga[4] = {0.f, 0.f, 0.f, 0.f};
        for (int k0 = 0; k0 < BD; k0 += 8) {
            float xq[4][8];
            #pragma unroll
            for (int r = 0; r < 4; ++r) {
                *reinterpret_cast<float4*>(&xq[r][0]) =
                    *reinterpret_cast<const float4*>(&xs[rbase + r][k0]);
                *reinterpret_cast<float4*>(&xq[r][4]) =
                    *reinterpret_cast<const float4*>(&xs[rbase + r][k0 + 4]);
            }
            #pragma unroll
            for (int kp = 0; kp < 4; ++kp) {
                const float4 w = pw[kp * HH];
                #pragma unroll
                for (int r = 0; r < 4; ++r) {
                    a1[r] = fmaf(xq[r][2 * kp],     w.x, a1[r]);
                    ga[r] = fmaf(xq[r][2 * kp],     w.y, ga[r]);
                    a1[r] = fmaf(xq[r][2 * kp + 1], w.z, a1[r]);
                    ga[r] = fmaf(xq[r][2 * kp + 1], w.w, ga[r]);
                }
            }
            pw += 4 * HH;
        }
        float bb1 = b1[c], bbg = bg1[c];
        #pragma unroll
        for (int r = 0; r < 4; ++r) {
            float v1 = __fadd_rn(a1[r], bb1);
            float vg = __fadd_rn(ga[r], bbg);
            h1s[rbase + r][c] = v1 > 0.f ? v1 : 0.f;
            g1f[(rbase + r) * HH + c] = vg > 0.f ? vg : 0.f;
        }
    }
    __syncthreads();

    // ---------- Phase 2: h2 = relu(h1@W2+b2), into cs-overlay (FROZEN) ----------
    {
        const int c = tid & (HH - 1);
        const int rbase = (tid >> 7) * 4;
        const float* __restrict__ pw = W2 + c;
        float acc[4] = {0.f, 0.f, 0.f, 0.f};
        for (int k0 = 0; k0 < HH; k0 += 8) {
            float hq[4][8];
            #pragma unroll
            for (int r = 0; r < 4; ++r) {
                *reinterpret_cast<float4*>(&hq[r][0]) =
                    *reinterpret_cast<const float4*>(&h1s[rbase + r][k0]);
                *reinterpret_cast<float4*>(&hq[r][4]) =
                    *reinterpret_cast<const float4*>(&h1s[rbase + r][k0 + 4]);
            }
            #pragma unroll
            for (int kk = 0; kk < 8; ++kk) {
                const float w = pw[kk * HH];
                #pragma unroll
                for (int r = 0; r < 4; ++r)
                    acc[r] = fmaf(hq[r][kk], w, acc[r]);
            }
            pw += 8 * HH;
        }
        float bb = b2[c];
        #pragma unroll
        for (int r = 0; r < 4; ++r) {
            float v = __fadd_rn(acc[r], bb);
            h2f[(rbase + r) * HH + c] = v > 0.f ? v : 0.f;
        }
    }
    __syncthreads();

    // ---------- Phase 3: cs = sig(h2@W3+b3) * sig(g1@Wg2+bg2) (FROZEN math) ----------
    // thread -> 2 cols x 8 rows; tid>>8 now spans 4 row-quarters -> 32 rows.
    {
        const int c2 = (tid & 255) * 2;      // column pair
        const int rb = (tid >> 8) * 8;       // row-quarter base (0,8,16,24)
        float zi[8][2], zg[8][2];
        #pragma unroll
        for (int r = 0; r < 8; ++r) { zi[r][0] = 0.f; zi[r][1] = 0.f; }
        {
            const float* __restrict__ pw = W3 + c2;
            for (int k0 = 0; k0 < HH; k0 += 4) {
                float2 wv[4];
                #pragma unroll
                for (int kk = 0; kk < 4; ++kk)
                    wv[kk] = *reinterpret_cast<const float2*>(&pw[kk * BD]);
                float hq[8][4];
                #pragma unroll
                for (int r = 0; r < 8; ++r)
                    *reinterpret_cast<float4*>(&hq[r][0]) =
                        *reinterpret_cast<const float4*>(&h2f[(rb + r) * HH + k0]);
                #pragma unroll
                for (int kk = 0; kk < 4; ++kk)
                    #pragma unroll
                    for (int r = 0; r < 8; ++r) {
                        zi[r][0] = fmaf(hq[r][kk], wv[kk].x, zi[r][0]);
                        zi[r][1] = fmaf(hq[r][kk], wv[kk].y, zi[r][1]);
                    }
                pw += 4 * BD;
            }
        }
        #pragma unroll
        for (int r = 0; r < 8; ++r) { zg[r][0] = 0.f; zg[r][1] = 0.f; }
        {
            const float* __restrict__ pw = Wg2 + c2;
            for (int k0 = 0; k0 < HH; k0 += 4) {
                float2 wv[4];
                #pragma unroll
                for (int kk = 0; kk < 4; ++kk)
                    wv[kk] = *reinterpret_cast<const float2*>(&pw[kk * BD]);
                float gq[8][4];
                #pragma unroll
                for (int r = 0; r < 8; ++r)
                    *reinterpret_cast<float4*>(&gq[r][0]) =
                        *reinterpret_cast<const float4*>(&g1f[(rb + r) * HH + k0]);
                #pragma unroll
                for (int kk = 0; kk < 4; ++kk)
                    #pragma unroll
                    for (int r = 0; r < 8; ++r) {
                        zg[r][0] = fmaf(gq[r][kk], wv[kk].x, zg[r][0]);
                        zg[r][1] = fmaf(gq[r][kk], wv[kk].y, zg[r][1]);
                    }
                pw += 4 * BD;
            }
        }
        __syncthreads();   // all h2/g1 reads complete before cs is overwritten
        float bi0 = b3[c2], bi1 = b3[c2 + 1];
        float bq0 = bg2[c2], bq1 = bg2[c2 + 1];
        #pragma unroll
        for (int r = 0; r < 8; ++r) {
            float2 v;
            v.x = __fmul_rn(sig_xla(__fadd_rn(zi[r][0], bi0)),
                            sig_xla(__fadd_rn(zg[r][0], bq0)));
            v.y = __fmul_rn(sig_xla(__fadd_rn(zi[r][1], bi1)),
                            sig_xla(__fadd_rn(zg[r][1], bq1)));
            *reinterpret_cast<float2*>(&cs[rb + r][c2]) = v;
        }
    }
    __syncthreads();

    // ---------- Phase 4: per-row top-K, exact on fp32 keys (FROZEN semantics) ----------
    // 16 waves, 32 rows: wave wv handles rows {wv, wv+16}.
    {
        const int lane = tid & 63;
        const int wv = tid >> 6;
        unsigned short* xsu = (unsigned short*)&xs[0][0];
        for (int rr = 0; rr < 2; ++rr) {
            const int r = wv + rr * 16;
            const float* __restrict__ pxr = x + (row0 + r) * BD;
            float xr[8];
            #pragma unroll
            for (int j = 0; j < 8; ++j) xr[j] = pxr[j * 64 + lane];   // issue early

            unsigned u[8];
            #pragma unroll
            for (int j = 0; j < 8; ++j)
                u[j] = __float_as_uint(cs[r][j * 64 + lane]);

            unsigned lo = 0u, hi = 0x3F800000u;
            while (lo < hi) {
                unsigned mid = lo + ((hi - lo) >> 1);
                int cnt = 0;
                #pragma unroll
                for (int j = 0; j < 8; ++j)
                    cnt += __popcll(__ballot(u[j] > mid));
                if (cnt < KSEL) hi = mid; else lo = mid + 1;
            }
            const unsigned T = lo;

            int ngt = 0, neq = 0;
            #pragma unroll
            for (int j = 0; j < 8; ++j) {
                ngt += __popcll(__ballot(u[j] > T));
                neq += __popcll(__ballot(u[j] == T));
            }
            const int m = KSEL - ngt;

            unsigned selbits = 0;
            #pragma unroll
            for (int j = 0; j < 8; ++j)
                if (u[j] > T) selbits |= (1u << j);

            if (neq == m) {
                #pragma unroll
                for (int j = 0; j < 8; ++j)
                    if (u[j] == T) selbits |= (1u << j);
            } else {
                int cnt8[8];
                #pragma unroll
                for (int j = 0; j < 8; ++j) cnt8[j] = 0;
                for (int jj = 0; jj < BD; ++jj) {
                    unsigned uj = __float_as_uint(cs[r][jj]);
                    if (uj == T) {
                        #pragma unroll
                        for (int j = 0; j < 8; ++j)
                            cnt8[j] += (u[j] == T && jj < (j * 64 + lane)) ? 1 : 0;
                    }
                }
                #pragma unroll
                for (int j = 0; j < 8; ++j)
                    if (u[j] == T && (ngt + cnt8[j]) < KSEL)
                        selbits |= (1u << j);
            }

            // write masked x as split planes (hi at [0,512), lo at [520,1032))
            #pragma unroll
            for (int j = 0; j < 8; ++j) {
                const int d = j * 64 + lane;
                float v = (selbits & (1u << j)) ? xr[j] : 0.0f;
                unsigned uu = __float_as_uint(v);
                float res = v - __uint_as_float(uu & 0xffff0000u);
                xsu[r * XSU_STRIDE + d] = (unsigned short)(uu >> 16);
                xsu[r * XSU_STRIDE + XL_OFF + d] =
                    (unsigned short)(__float_as_uint(res) >> 16);
            }
        }
    }
    __syncthreads();

    // ---------- Phase R1 (MFMA): rs = relu(maskedX @ Wr1 + br1) ----------
    // 16 waves: wtile = w>>3 picks the 16-row half; jw = w&7 picks the 16-col tile.
    {
        const int lane = tid & 63;
        const int w = tid >> 6;
        const int wtile = w >> 3;
        const int jw = w & 7;
        const int arow = wtile * 16 + (lane & 15);
        const int kb = (lane >> 4) * 8;
        const int j0 = jw * 16;
        const int col = lane & 15;
        const unsigned short* xsu = (const unsigned short*)&xs[0][0];
        const bf16x8* pBh = reinterpret_cast<const bf16x8*>(p1h) + jw * 16 * 64 + lane;
        const bf16x8* pBl = reinterpret_cast<const bf16x8*>(p1l) + jw * 16 * 64 + lane;
        f32x4 acc = {0.f, 0.f, 0.f, 0.f};
        #pragma unroll 2
        for (int kt = 0; kt < 16; ++kt) {
            const int k0 = kt * 32 + kb;
            bf16x8 ah = *reinterpret_cast<const bf16x8*>(&xsu[arow * XSU_STRIDE + k0]);
            bf16x8 al = *reinterpret_cast<const bf16x8*>(&xsu[arow * XSU_STRIDE + XL_OFF + k0]);
            bf16x8 bh = pBh[kt * 64];
            bf16x8 bl = pBl[kt * 64];
            acc = __builtin_amdgcn_mfma_f32_16x16x32_bf16(ah, bh, acc, 0, 0, 0);
            acc = __builtin_amdgcn_mfma_f32_16x16x32_bf16(ah, bl, acc, 0, 0, 0);
            acc = __builtin_amdgcn_mfma_f32_16x16x32_bf16(al, bh, acc, 0, 0, 0);
        }
        float bias = br1[j0 + col];
        unsigned short* rsu = (unsigned short*)&h1s[0][0];
        #pragma unroll
        for (int reg = 0; reg < 4; ++reg) {
            const int rr = wtile * 16 + (lane >> 4) * 4 + reg;
            float v = acc[reg] + bias;
            v = v > 0.f ? v : 0.f;
            unsigned uu = __float_as_uint(v);
            float res = v - __uint_as_float(uu & 0xffff0000u);
            rsu[rr * RS_STRIDE + j0 + col] = (unsigned short)(uu >> 16);
            rsu[rr * RS_STRIDE + RSL_OFF + j0 + col] =
                (unsigned short)(__float_as_uint(res) >> 16);
        }
    }
    __syncthreads();

    // ---------- Phase R2 (MFMA): out = rs @ Wr2 + br2 ----------
    // wtile = w>>3 picks the 16-row half; jt strides 8 over the 23 col tiles.
    {
        const int lane = tid & 63;
        const int w = tid >> 6;
        const int wtile = w >> 3;
        const int arow = wtile * 16 + (lane & 15);
        const int kb = (lane >> 4) * 8;
        const int col = lane & 15;
        const unsigned short* rsu = (const unsigned short*)&h1s[0][0];
        bf16x8 ah[4], al[4];
        #pragma unroll
        for (int kt = 0; kt < 4; ++kt) {
            const int k0 = kt * 32 + kb;
            ah[kt] = *reinterpret_cast<const bf16x8*>(&rsu[arow * RS_STRIDE + k0]);
            al[kt] = *reinterpret_cast<const bf16x8*>(&rsu[arow * RS_STRIDE + RSL_OFF + k0]);
        }
        for (int jt = (w & 7); jt < 23; jt += 8) {
            const int cc = jt * 16 + col;
            const bf16x8* pBh = reinterpret_cast<const bf16x8*>(p2h) + jt * 4 * 64 + lane;
            const bf16x8* pBl = reinterpret_cast<const bf16x8*>(p2l) + jt * 4 * 64 + lane;
            f32x4 acc = {0.f, 0.f, 0.f, 0.f};
            #pragma unroll
            for (int kt = 0; kt < 4; ++kt) {
                bf16x8 bh = pBh[kt * 64];
                bf16x8 bl = pBl[kt * 64];
                acc = __builtin_amdgcn_mfma_f32_16x16x32_bf16(ah[kt], bh, acc, 0, 0, 0);
                acc = __builtin_amdgcn_mfma_f32_16x16x32_bf16(ah[kt], bl, acc, 0, 0, 0);
                acc = __builtin_amdgcn_mfma_f32_16x16x32_bf16(al[kt], bh, acc, 0, 0, 0);
            }
            if (cc < KSEL) {
                float bias = br2[cc];
                #pragma unroll
                for (int reg = 0; reg < 4; ++reg) {
                    const int rr = wtile * 16 + (lane >> 4) * 4 + reg;
                    out[(row0 + rr) * KSEL + cc] = acc[reg] + bias;
                }
            }
        }
    }
}

extern "C" void kernel_launch(void* const* d_in, const int* in_sizes, int n_in,
                              void* d_out, int out_size, void* d_ws, size_t ws_size,
                              hipStream_t stream) {
    const float* x   = (const float*)d_in[0];
    const float* W1  = (const float*)d_in[1];
    const float* b1  = (const float*)d_in[2];
    const float* W2  = (const float*)d_in[3];
    const float* b2  = (const float*)d_in[4];
    const float* W3  = (const float*)d_in[5];
    const float* b3  = (const float*)d_in[6];
    const float* Wg1 = (const float*)d_in[7];
    const float* bg1 = (const float*)d_in[8];
    const float* Wg2 = (const float*)d_in[9];
    const float* bg2 = (const float*)d_in[10];
    const float* Wr1 = (const float*)d_in[11];
    const float* br1 = (const float*)d_in[12];
    const float* Wr2 = (const float*)d_in[13];
    const float* br2 = (const float*)d_in[14];
    float* out = (float*)d_out;

    // ws layout (IDENTICAL to rounds 19/21, 974848 B total — proven safe):
    // pk1 (512 KB) | p1h/p1l (131072 B each) | p2h/p2l (94208 B each)
    float4* pk1 = (float4*)d_ws;
    unsigned short* p1h = (unsigned short*)(pk1 + 256 * HH);
    unsigned short* p1l = p1h + BD * HH;
    unsigned short* p2h = p1l + BD * HH;
    unsigned short* p2l = p2h + P2N;

    prepack_w1<<<dim3((256 * HH + 255) / 256), dim3(256), 0, stream>>>(W1, Wg1, pk1);
    const int npack = 8 * 16 * 64 + 23 * 4 * 64;   // 14080 threads
    prepack<<<dim3((npack + 255) / 256), dim3(256), 0, stream>>>(
        Wr1, Wr2, p1h, p1l, p2h, p2l);

    const int nrows = in_sizes[0] / BD;          // 65536
    dim3 grid(nrows / TR), block(NT);            // 2048 blocks x 1024 threads
    afs_fused<<<grid, block, 0, stream>>>(x, pk1, b1, W2, b2, W3, b3,
                                          bg1, Wg2, bg2, br1, br2,
                                          p1h, p1l, p2h, p2l, out);
}

// Round 23
// 747.716 us; speedup vs baseline: 1.1107x; 1.1107x over previous
//
#include <hip/hip_runtime.h>
#include <math.h>

#define BD 512      // input dim D
#define HH 128      // hidden dim H
#define KSEL 358    // output dim K (top-k)
#define TR 16       // rows per block
#define NT 512      // threads per block (8 waves)
#define XP 4        // xs row pad (floats)
#define HP 4        // h1s row pad (floats)

#define XSU_STRIDE ((BD + XP) * 2)   // 1032 ushorts per xs row
#define XL_OFF 520                   // xl plane offset (16B-aligned reads)
#define RS_STRIDE ((HH + HP) * 2)    // 264 ushorts per rs row
#define RSL_OFF 136                  // rl plane offset (16B-aligned reads)

#define P2N (23 * 4 * 64 * 8)        // packed Wr2 elements = 47104

typedef __attribute__((ext_vector_type(8))) short bf16x8;
typedef __attribute__((ext_vector_type(4))) float f32x4;

// XLA:CPU / Eigen pexp-float (classic cephes) bit-emulation. FROZEN — this
// matches the grading reference bit-for-bit (round 5 PASS, absmax 0.0039,
// zero mask flips). Do not alter any operation or rounding mode here.
__device__ __forceinline__ float cephes_expf(float x) {
    x = fminf(x, 88.3762626647950f);
    x = fmaxf(x, -88.3762626647949f);
    float m = floorf(fmaf(x, 1.44269504088896341f, 0.5f));
    float r = __fsub_rn(x, __fmul_rn(m, 0.693359375f));
    r = __fsub_rn(r, __fmul_rn(m, -2.12194440e-4f));
    float r2 = __fmul_rn(r, r);
    float p = 1.9875691500E-4f;
    p = fmaf(p, r, 1.3981999507E-3f);
    p = fmaf(p, r, 8.3334519073E-3f);
    p = fmaf(p, r, 4.1665795894E-2f);
    p = fmaf(p, r, 1.6666665459E-1f);
    p = fmaf(p, r, 5.0000001201E-1f);
    float y = __fadd_rn(fmaf(p, r2, r), 1.0f);
    int mi = (int)m;
    y = __int_as_float(__float_as_int(y) + (mi << 23));
    return y;
}

__device__ __forceinline__ float sig_xla(float z) {
    float t = cephes_expf(-z);
    float d = __fadd_rn(1.0f, t);
    return __fdiv_rn(1.0f, d);
}

// Prologue A: interleave W1||Wg1 into k-pair float4 quads:
// pk1[p*HH + c] = {W1[2p][c], Wg1[2p][c], W1[2p+1][c], Wg1[2p+1][c]}.
__global__ void prepack_w1(const float* __restrict__ W1, const float* __restrict__ Wg1,
                           float4* __restrict__ pk1)
{
    const int t = blockIdx.x * blockDim.x + threadIdx.x;   // p*HH + c
    if (t < 256 * HH) {
        const int p = t >> 7, c = t & (HH - 1);
        float4 v;
        v.x = W1 [(2 * p)     * HH + c];
        v.y = Wg1[(2 * p)     * HH + c];
        v.z = W1 [(2 * p + 1) * HH + c];
        v.w = Wg1[(2 * p + 1) * HH + c];
        pk1[t] = v;
    }
}

// Prologue B: pack recon weights into MFMA B-fragment lane order, pre-split
// into hi/lo bf16 planes (truncation split: identical bits to in-kernel
// split -> recon arithmetic bit-identical).
__global__ void prepack(const float* __restrict__ Wr1, const float* __restrict__ Wr2,
                        unsigned short* __restrict__ p1h, unsigned short* __restrict__ p1l,
                        unsigned short* __restrict__ p2h, unsigned short* __restrict__ p2l)
{
    const int t = blockIdx.x * blockDim.x + threadIdx.x;
    if (t < 8 * 16 * 64) {
        const int jb = t >> 10, kt = (t >> 6) & 15, lane = t & 63;
        const int col = lane & 15, kg = lane >> 4;
        const int base = t * 8;
        #pragma unroll
        for (int s = 0; s < 8; ++s) {
            const int k = kt * 32 + kg * 8 + s;
            float v = Wr1[k * HH + jb * 16 + col];
            unsigned u = __float_as_uint(v);
            p1h[base + s] = (unsigned short)(u >> 16);
            float res = v - __uint_as_float(u & 0xffff0000u);
            p1l[base + s] = (unsigned short)(__float_as_uint(res) >> 16);
        }
    }
    const int t2 = t - 8 * 16 * 64;
    if (t2 >= 0 && t2 < 23 * 4 * 64) {
        const int jt = t2 >> 8, kt = (t2 >> 6) & 3, lane = t2 & 63;
        const int col = lane & 15, kg = lane >> 4;
        const int cg = jt * 16 + col;
        const int base = t2 * 8;
        #pragma unroll
        for (int s = 0; s < 8; ++s) {
            const int k = kt * 32 + kg * 8 + s;
            float v = (cg < KSEL) ? Wr2[k * KSEL + cg] : 0.f;
            unsigned u = __float_as_uint(v);
            p2h[base + s] = (unsigned short)(u >> 16);
            float res = v - __uint_as_float(u & 0xffff0000u);
            p2l[base + s] = (unsigned short)(__float_as_uint(res) >> 16);
        }
    }
}

__global__ __launch_bounds__(NT, 4)   // VGPR cap 128: NO spill (r10/r14 lesson)
void afs_fused(const float* __restrict__ x,
               const float4* __restrict__ pk1, const float* __restrict__ b1,
               const float* __restrict__ W2,  const float* __restrict__ b2,
               const float* __restrict__ W3,  const float* __restrict__ b3,
               const float* __restrict__ bg1,
               const float* __restrict__ Wg2, const float* __restrict__ bg2,
               const float* __restrict__ br1,
               const float* __restrict__ br2,
               const unsigned short* __restrict__ p1h, const unsigned short* __restrict__ p1l,
               const unsigned short* __restrict__ p2h, const unsigned short* __restrict__ p2l,
               float* __restrict__ out)
{
    // 74240 B total -> 2 blocks/CU, 16 waves/CU (r21 champion layout; r22
    // proved 1 block/CU loses barrier overlap -> keep 2 blocks/CU).
    __shared__ float xs[TR][BD + XP];   // 33024 B; x fp32 -> split bf16 planes in P4
    __shared__ float h1s[TR][HH + HP];  //  8448 B; h1 -> split r planes after R1
    __shared__ float cs[TR][BD];        // 32768 B; h2[0..2048) + g1[2048..4096) -> scores

    float* h2f = &cs[0][0];             // h2[r][k] == h2f[r*HH+k]
    float* g1f = &cs[0][0] + TR * HH;   // g1[r][k] == g1f[r*HH+k]

    const int tid = threadIdx.x;
    const long long row0 = (long long)blockIdx.x * TR;

    // ---------- Phase 0: load x tile (row-wise, padded dest) ----------
    {
        #pragma unroll
        for (int i = tid; i < TR * (BD / 4); i += NT) {
            const int r = i >> 7;           // BD/4 = 128
            const int c4 = (i & 127) * 4;
            *reinterpret_cast<float4*>(&xs[r][c4]) =
                *reinterpret_cast<const float4*>(&x[(row0 + r) * BD + c4]);
        }
    }
    __syncthreads();

    // ---------- Phase 1: h1 = relu(x@W1+b1), g1 = relu(x@Wg1+bg1) (FROZEN math) ----------
    {
        const int c = tid & (HH - 1);
        const int rbase = (tid >> 7) * 4;
        const float4* __restrict__ pw = pk1 + c;
        float a1[4] = {0.f, 0.f, 0.f, 0.f};
        float ga[4] = {0.f, 0.f, 0.f, 0.f};
        for (int k0 = 0; k0 < BD; k0 += 8) {
            float xq[4][8];
            #pragma unroll
            for (int r = 0; r < 4; ++r) {
                *reinterpret_cast<float4*>(&xq[r][0]) =
                    *reinterpret_cast<const float4*>(&xs[rbase + r][k0]);
                *reinterpret_cast<float4*>(&xq[r][4]) =
                    *reinterpret_cast<const float4*>(&xs[rbase + r][k0 + 4]);
            }
            #pragma unroll
            for (int kp = 0; kp < 4; ++kp) {
                const float4 w = pw[kp * HH];
                #pragma unroll
                for (int r = 0; r < 4; ++r) {
                    a1[r] = fmaf(xq[r][2 * kp],     w.x, a1[r]);
                    ga[r] = fmaf(xq[r][2 * kp],     w.y, ga[r]);
                    a1[r] = fmaf(xq[r][2 * kp + 1], w.z, a1[r]);
                    ga[r] = fmaf(xq[r][2 * kp + 1], w.w, ga[r]);
                }
            }
            pw += 4 * HH;
        }
        float bb1 = b1[c], bbg = bg1[c];
        #pragma unroll
        for (int r = 0; r < 4; ++r) {
            float v1 = __fadd_rn(a1[r], bb1);
            float vg = __fadd_rn(ga[r], bbg);
            h1s[rbase + r][c] = v1 > 0.f ? v1 : 0.f;
            g1f[(rbase + r) * HH + c] = vg > 0.f ? vg : 0.f;
        }
    }
    __syncthreads();

    // ---------- Phase 2: h2 = relu(h1@W2+b2), into cs-overlay (FROZEN) ----------
    {
        const int c = tid & (HH - 1);
        const int rbase = (tid >> 7) * 4;
        const float* __restrict__ pw = W2 + c;
        float acc[4] = {0.f, 0.f, 0.f, 0.f};
        for (int k0 = 0; k0 < HH; k0 += 8) {
            float hq[4][8];
            #pragma unroll
            for (int r = 0; r < 4; ++r) {
                *reinterpret_cast<float4*>(&hq[r][0]) =
                    *reinterpret_cast<const float4*>(&h1s[rbase + r][k0]);
                *reinterpret_cast<float4*>(&hq[r][4]) =
                    *reinterpret_cast<const float4*>(&h1s[rbase + r][k0 + 4]);
            }
            #pragma unroll
            for (int kk = 0; kk < 8; ++kk) {
                const float w = pw[kk * HH];
                #pragma unroll
                for (int r = 0; r < 4; ++r)
                    acc[r] = fmaf(hq[r][kk], w, acc[r]);
            }
            pw += 8 * HH;
        }
        float bb = b2[c];
        #pragma unroll
        for (int r = 0; r < 4; ++r) {
            float v = __fadd_rn(acc[r], bb);
            h2f[(rbase + r) * HH + c] = v > 0.f ? v : 0.f;
        }
    }
    __syncthreads();

    // ---------- Phase 3: cs = sig(h2@W3+b3) * sig(g1@Wg2+bg2) (FROZEN math) ----------
    // thread -> 2 cols x 8 rows (r21 mapping).
    {
        const int c2 = (tid & 255) * 2;      // column pair
        const int rb = (tid >> 8) * 8;       // row-half base (0 or 8)
        float zi[8][2], zg[8][2];
        #pragma unroll
        for (int r = 0; r < 8; ++r) { zi[r][0] = 0.f; zi[r][1] = 0.f; }
        {
            const float* __restrict__ pw = W3 + c2;
            for (int k0 = 0; k0 < HH; k0 += 4) {
                float2 wv[4];
                #pragma unroll
                for (int kk = 0; kk < 4; ++kk)
                    wv[kk] = *reinterpret_cast<const float2*>(&pw[kk * BD]);
                float hq[8][4];
                #pragma unroll
                for (int r = 0; r < 8; ++r)
                    *reinterpret_cast<float4*>(&hq[r][0]) =
                        *reinterpret_cast<const float4*>(&h2f[(rb + r) * HH + k0]);
                #pragma unroll
                for (int kk = 0; kk < 4; ++kk)
                    #pragma unroll
                    for (int r = 0; r < 8; ++r) {
                        zi[r][0] = fmaf(hq[r][kk], wv[kk].x, zi[r][0]);
                        zi[r][1] = fmaf(hq[r][kk], wv[kk].y, zi[r][1]);
                    }
                pw += 4 * BD;
            }
        }
        #pragma unroll
        for (int r = 0; r < 8; ++r) { zg[r][0] = 0.f; zg[r][1] = 0.f; }
        {
            const float* __restrict__ pw = Wg2 + c2;
            for (int k0 = 0; k0 < HH; k0 += 4) {
                float2 wv[4];
                #pragma unroll
                for (int kk = 0; kk < 4; ++kk)
                    wv[kk] = *reinterpret_cast<const float2*>(&pw[kk * BD]);
                float gq[8][4];
                #pragma unroll
                for (int r = 0; r < 8; ++r)
                    *reinterpret_cast<float4*>(&gq[r][0]) =
                        *reinterpret_cast<const float4*>(&g1f[(rb + r) * HH + k0]);
                #pragma unroll
                for (int kk = 0; kk < 4; ++kk)
                    #pragma unroll
                    for (int r = 0; r < 8; ++r) {
                        zg[r][0] = fmaf(gq[r][kk], wv[kk].x, zg[r][0]);
                        zg[r][1] = fmaf(gq[r][kk], wv[kk].y, zg[r][1]);
                    }
                pw += 4 * BD;
            }
        }
        __syncthreads();   // all h2/g1 reads complete before cs is overwritten
        float bi0 = b3[c2], bi1 = b3[c2 + 1];
        float bq0 = bg2[c2], bq1 = bg2[c2 + 1];
        #pragma unroll
        for (int r = 0; r < 8; ++r) {
            float2 v;
            v.x = __fmul_rn(sig_xla(__fadd_rn(zi[r][0], bi0)),
                            sig_xla(__fadd_rn(zg[r][0], bq0)));
            v.y = __fmul_rn(sig_xla(__fadd_rn(zi[r][1], bi1)),
                            sig_xla(__fadd_rn(zg[r][1], bq1)));
            *reinterpret_cast<float2*>(&cs[rb + r][c2]) = v;
        }
    }
    __syncthreads();

    // ---------- Phase 4: per-row top-K, exact on fp32 keys (FROZEN semantics) ----------
    // xr now read from xs LDS (identical fp32 bits; P1 was the last reader;
    // this wave exclusively owns row r, and all reads precede the plane
    // writes below). Saves the 60 MB global x re-read.
    {
        const int lane = tid & 63;
        const int wv = tid >> 6;
        unsigned short* xsu = (unsigned short*)&xs[0][0];
        for (int rr = 0; rr < 2; ++rr) {
            const int r = wv + rr * 8;
            float xr[8];
            #pragma unroll
            for (int j = 0; j < 8; ++j) xr[j] = xs[r][j * 64 + lane];

            unsigned u[8];
            #pragma unroll
            for (int j = 0; j < 8; ++j)
                u[j] = __float_as_uint(cs[r][j * 64 + lane]);

            unsigned lo = 0u, hi = 0x3F800000u;
            while (lo < hi) {
                unsigned mid = lo + ((hi - lo) >> 1);
                int cnt = 0;
                #pragma unroll
                for (int j = 0; j < 8; ++j)
                    cnt += __popcll(__ballot(u[j] > mid));
                if (cnt < KSEL) hi = mid; else lo = mid + 1;
            }
            const unsigned T = lo;

            int ngt = 0, neq = 0;
            #pragma unroll
            for (int j = 0; j < 8; ++j) {
                ngt += __popcll(__ballot(u[j] > T));
                neq += __popcll(__ballot(u[j] == T));
            }
            const int m = KSEL - ngt;

            unsigned selbits = 0;
            #pragma unroll
            for (int j = 0; j < 8; ++j)
                if (u[j] > T) selbits |= (1u << j);

            if (neq == m) {
                #pragma unroll
                for (int j = 0; j < 8; ++j)
                    if (u[j] == T) selbits |= (1u << j);
            } else {
                int cnt8[8];
                #pragma unroll
                for (int j = 0; j < 8; ++j) cnt8[j] = 0;
                for (int jj = 0; jj < BD; ++jj) {
                    unsigned uj = __float_as_uint(cs[r][jj]);
                    if (uj == T) {
                        #pragma unroll
                        for (int j = 0; j < 8; ++j)
                            cnt8[j] += (u[j] == T && jj < (j * 64 + lane)) ? 1 : 0;
                    }
                }
                #pragma unroll
                for (int j = 0; j < 8; ++j)
                    if (u[j] == T && (ngt + cnt8[j]) < KSEL)
                        selbits |= (1u << j);
            }

            // write masked x as split planes (hi at [0,512), lo at [520,1032))
            #pragma unroll
            for (int j = 0; j < 8; ++j) {
                const int d = j * 64 + lane;
                float v = (selbits & (1u << j)) ? xr[j] : 0.0f;
                unsigned uu = __float_as_uint(v);
                float res = v - __uint_as_float(uu & 0xffff0000u);
                xsu[r * XSU_STRIDE + d] = (unsigned short)(uu >> 16);
                xsu[r * XSU_STRIDE + XL_OFF + d] =
                    (unsigned short)(__float_as_uint(res) >> 16);
            }
        }
    }
    __syncthreads();

    // ---------- Phase R1 (MFMA): rs = relu(maskedX @ Wr1 + br1) ----------
    {
        const int lane = tid & 63;
        const int w = tid >> 6;
        const int arow = lane & 15;
        const int kb = (lane >> 4) * 8;
        const int j0 = w * 16;
        const int col = lane & 15;
        const unsigned short* xsu = (const unsigned short*)&xs[0][0];
        const bf16x8* pBh = reinterpret_cast<const bf16x8*>(p1h) + w * 16 * 64 + lane;
        const bf16x8* pBl = reinterpret_cast<const bf16x8*>(p1l) + w * 16 * 64 + lane;
        f32x4 acc = {0.f, 0.f, 0.f, 0.f};
        #pragma unroll 2
        for (int kt = 0; kt < 16; ++kt) {
            const int k0 = kt * 32 + kb;
            bf16x8 ah = *reinterpret_cast<const bf16x8*>(&xsu[arow * XSU_STRIDE + k0]);
            bf16x8 al = *reinterpret_cast<const bf16x8*>(&xsu[arow * XSU_STRIDE + XL_OFF + k0]);
            bf16x8 bh = pBh[kt * 64];
            bf16x8 bl = pBl[kt * 64];
            acc = __builtin_amdgcn_mfma_f32_16x16x32_bf16(ah, bh, acc, 0, 0, 0);
            acc = __builtin_amdgcn_mfma_f32_16x16x32_bf16(ah, bl, acc, 0, 0, 0);
            acc = __builtin_amdgcn_mfma_f32_16x16x32_bf16(al, bh, acc, 0, 0, 0);
        }
        float bias = br1[j0 + col];
        unsigned short* rsu = (unsigned short*)&h1s[0][0];
        #pragma unroll
        for (int reg = 0; reg < 4; ++reg) {
            const int rr = (lane >> 4) * 4 + reg;
            float v = acc[reg] + bias;
            v = v > 0.f ? v : 0.f;
            unsigned uu = __float_as_uint(v);
            float res = v - __uint_as_float(uu & 0xffff0000u);
            rsu[rr * RS_STRIDE + j0 + col] = (unsigned short)(uu >> 16);
            rsu[rr * RS_STRIDE + RSL_OFF + j0 + col] =
                (unsigned short)(__float_as_uint(res) >> 16);
        }
    }
    __syncthreads();

    // ---------- Phase R2 (MFMA): out = rs @ Wr2 + br2 ----------
    {
        const int lane = tid & 63;
        const int w = tid >> 6;
        const int arow = lane & 15;
        const int kb = (lane >> 4) * 8;
        const int col = lane & 15;
        const unsigned short* rsu = (const unsigned short*)&h1s[0][0];
        bf16x8 ah[4], al[4];
        #pragma unroll
        for (int kt = 0; kt < 4; ++kt) {
            const int k0 = kt * 32 + kb;
            ah[kt] = *reinterpret_cast<const bf16x8*>(&rsu[arow * RS_STRIDE + k0]);
            al[kt] = *reinterpret_cast<const bf16x8*>(&rsu[arow * RS_STRIDE + RSL_OFF + k0]);
        }
        for (int jt = w; jt < 23; jt += 8) {
            const int cc = jt * 16 + col;
            const bf16x8* pBh = reinterpret_cast<const bf16x8*>(p2h) + jt * 4 * 64 + lane;
            const bf16x8* pBl = reinterpret_cast<const bf16x8*>(p2l) + jt * 4 * 64 + lane;
            f32x4 acc = {0.f, 0.f, 0.f, 0.f};
            #pragma unroll
            for (int kt = 0; kt < 4; ++kt) {
                bf16x8 bh = pBh[kt * 64];
                bf16x8 bl = pBl[kt * 64];
                acc = __builtin_amdgcn_mfma_f32_16x16x32_bf16(ah[kt], bh, acc, 0, 0, 0);
                acc = __builtin_amdgcn_mfma_f32_16x16x32_bf16(ah[kt], bl, acc, 0, 0, 0);
                acc = __builtin_amdgcn_mfma_f32_16x16x32_bf16(al[kt], bh, acc, 0, 0, 0);
            }
            if (cc < KSEL) {
                float bias = br2[cc];
                #pragma unroll
                for (int reg = 0; reg < 4; ++reg) {
                    const int rr = (lane >> 4) * 4 + reg;
                    out[(row0 + rr) * KSEL + cc] = acc[reg] + bias;
                }
            }
        }
    }
}

extern "C" void kernel_launch(void* const* d_in, const int* in_sizes, int n_in,
                              void* d_out, int out_size, void* d_ws, size_t ws_size,
                              hipStream_t stream) {
    const float* x   = (const float*)d_in[0];
    const float* W1  = (const float*)d_in[1];
    const float* b1  = (const float*)d_in[2];
    const float* W2  = (const float*)d_in[3];
    const float* b2  = (const float*)d_in[4];
    const float* W3  = (const float*)d_in[5];
    const float* b3  = (const float*)d_in[6];
    const float* Wg1 = (const float*)d_in[7];
    const float* bg1 = (const float*)d_in[8];
    const float* Wg2 = (const float*)d_in[9];
    const float* bg2 = (const float*)d_in[10];
    const float* Wr1 = (const float*)d_in[11];
    const float* br1 = (const float*)d_in[12];
    const float* Wr2 = (const float*)d_in[13];
    const float* br2 = (const float*)d_in[14];
    float* out = (float*)d_out;

    // ws layout (IDENTICAL to rounds 19/21, 974848 B total — proven safe):
    // pk1 (512 KB) | p1h/p1l (131072 B each) | p2h/p2l (94208 B each)
    float4* pk1 = (float4*)d_ws;
    unsigned short* p1h = (unsigned short*)(pk1 + 256 * HH);
    unsigned short* p1l = p1h + BD * HH;
    unsigned short* p2h = p1l + BD * HH;
    unsigned short* p2l = p2h + P2N;

    prepack_w1<<<dim3((256 * HH + 255) / 256), dim3(256), 0, stream>>>(W1, Wg1, pk1);
    const int npack = 8 * 16 * 64 + 23 * 4 * 64;   // 14080 threads
    prepack<<<dim3((npack + 255) / 256), dim3(256), 0, stream>>>(
        Wr1, Wr2, p1h, p1l, p2h, p2l);

    const int nrows = in_sizes[0] / BD;          // 65536
    dim3 grid(nrows / TR), block(NT);
    afs_fused<<<grid, block, 0, stream>>>(x, pk1, b1, W2, b2, W3, b3,
                                          bg1, Wg2, bg2, br1, br2,
                                          p1h, p1l, p2h, p2l, out);
}